// Round 5
// baseline (327.783 us; speedup 1.0000x reference)
//
#include <hip/hip_runtime.h>

// ---------------------------------------------------------------------------
// GCN 2-layer pipeline:
//   h1 = relu(spmm(A, x@W1) + b1); out = relu(spmm(A, h1@W2) + b2)
// CSR build: bucket sort (row>>8) -> per-bucket LDS scatter (L2-resident).
// gemm1: MFMA bf16 (K=128 LDS-resident). Layer 2: agg1+gemm2 FUSED
// (block aggregates 32 rows into LDS bf16, then MFMA @W2 -> sup2).
// Aggregation gathers: full wave per edge (2 cols/lane), 8-edge MLP unroll.
// ---------------------------------------------------------------------------

typedef unsigned int uint;
typedef unsigned short ushort;
typedef __attribute__((ext_vector_type(8))) short bf16x8;
typedef __attribute__((ext_vector_type(4))) float f32x4;

#define RPB_SHIFT 8
#define RPB 256          // rows per bucket
#define MAXB 512         // max buckets (N <= 131072)
#define CH 2048          // edges per bin-block

__device__ __forceinline__ ushort f2bf(float f) {   // RNE float->bf16
    uint u = __float_as_uint(f);
    u += 0x7fffu + ((u >> 16) & 1u);
    return (ushort)(u >> 16);
}
__device__ __forceinline__ float bflo(uint p) { return __uint_as_float(p << 16); }
__device__ __forceinline__ float bfhi(uint p) { return __uint_as_float(p & 0xffff0000u); }

// ---------------- prep: Wt transpose->bf16 + zero bcnt ----------------
__global__ __launch_bounds__(256) void prep_kernel(const float* __restrict__ W1,
                                                   const float* __restrict__ W2,
                                                   ushort* __restrict__ Wt1,
                                                   ushort* __restrict__ Wt2,
                                                   int* __restrict__ bcnt) {
    int g = blockIdx.x * 256 + threadIdx.x;
    if (g < 16384) { int k = g >> 7, n = g & 127; Wt1[n * 128 + k] = f2bf(W1[g]); }
    else if (g < 24576) { int i = g - 16384; int k = i >> 6, n = i & 63; Wt2[n * 128 + k] = f2bf(W2[i]); }
    if (g < MAXB) bcnt[g] = 0;
}

// ---------------- CSR build ----------------

__global__ __launch_bounds__(256) void bucket_hist(const int* __restrict__ row,
                                                   int* __restrict__ bcnt,
                                                   int E, int nbuckets) {
    __shared__ int h[MAXB];
    int t = threadIdx.x;
    h[t] = 0; h[t + 256] = 0;
    __syncthreads();
    int stride = gridDim.x * blockDim.x;
    for (int e = blockIdx.x * blockDim.x + t; e < E; e += stride)
        atomicAdd(&h[row[e] >> RPB_SHIFT], 1);
    __syncthreads();
    if (h[t] > 0)       atomicAdd(&bcnt[t], h[t]);
    if (h[t + 256] > 0) atomicAdd(&bcnt[t + 256], h[t + 256]);
}

// exclusive scan of bucket counts (512 entries, 2/thread); init cursors.
__global__ __launch_bounds__(256) void bucket_scan(const int* __restrict__ bcnt,
                                                   int* __restrict__ bbase,
                                                   int* __restrict__ bcur,
                                                   int* __restrict__ rowptr,
                                                   int nbuckets, int N, int E) {
    __shared__ int s[256];
    int t = threadIdx.x;
    int c0 = bcnt[2 * t], c1 = bcnt[2 * t + 1];
    s[t] = c0 + c1;
    __syncthreads();
    for (int off = 1; off < 256; off <<= 1) {
        int v = (t >= off) ? s[t - off] : 0;
        __syncthreads();
        s[t] += v;
        __syncthreads();
    }
    int excl = s[t] - c0 - c1;
    if (2 * t < nbuckets)     { bbase[2 * t] = excl;          bcur[2 * t] = excl; }
    if (2 * t + 1 < nbuckets) { bbase[2 * t + 1] = excl + c0; bcur[2 * t + 1] = excl + c0; }
    if (t == 0) { bbase[nbuckets] = E; rowptr[N] = E; }
}

// bin: stage CH edges, counting-sort by bucket in LDS, burst-write per bucket.
__global__ __launch_bounds__(256) void bin_kernel(
        const int* __restrict__ row, const int* __restrict__ col,
        const float* __restrict__ val, int* __restrict__ bcur,
        int* __restrict__ brow, int2* __restrict__ bcolval, int E) {
    __shared__ int ssrow[CH];
    __shared__ int2 scolval[CH];
    __shared__ int hist[MAXB], lbase[MAXB], cur[MAXB], gbase[MAXB];
    __shared__ int s[256];
    int t = threadIdx.x;
    int c0 = blockIdx.x * CH;

    hist[t] = 0; hist[t + 256] = 0;
    __syncthreads();

    int rr[8]; int2 rc[8];
    #pragma unroll
    for (int k = 0; k < 8; ++k) {
        int e = c0 + (k << 8) + t;
        if (e < E) {
            rr[k] = row[e];
            rc[k] = make_int2(col[e], __float_as_int(val[e]));
            atomicAdd(&hist[rr[k] >> RPB_SHIFT], 1);
        } else rr[k] = -1;
    }
    __syncthreads();

    int h0 = hist[2 * t], h1 = hist[2 * t + 1];
    s[t] = h0 + h1;
    __syncthreads();
    for (int off = 1; off < 256; off <<= 1) {
        int v = (t >= off) ? s[t - off] : 0;
        __syncthreads();
        s[t] += v;
        __syncthreads();
    }
    int excl = s[t] - h0 - h1;
    lbase[2 * t] = excl;          cur[2 * t] = excl;
    lbase[2 * t + 1] = excl + h0; cur[2 * t + 1] = excl + h0;
    __syncthreads();
    int total = s[255];

    #pragma unroll
    for (int k = 0; k < 8; ++k) {
        if (rr[k] >= 0) {
            int b = rr[k] >> RPB_SHIFT;
            int p = atomicAdd(&cur[b], 1);
            ssrow[p]   = rr[k];
            scolval[p] = rc[k];
        }
    }
    if (h0 > 0) gbase[2 * t]     = atomicAdd(&bcur[2 * t], h0);
    if (h1 > 0) gbase[2 * t + 1] = atomicAdd(&bcur[2 * t + 1], h1);
    __syncthreads();

    for (int i = t; i < total; i += 256) {
        int r = ssrow[i];
        int b = r >> RPB_SHIFT;
        int g = gbase[b] + (i - lbase[b]);
        brow[g]    = r;
        bcolval[g] = scolval[i];
    }
}

// final: one block per bucket; LDS row hist/scan/cursors; L2-window scatter.
__global__ __launch_bounds__(256) void final_scatter(
        const int* __restrict__ bbase, const int* __restrict__ brow,
        const int2* __restrict__ bcolval, int* __restrict__ rowptr,
        int2* __restrict__ csr, int N) {
    __shared__ int h[RPB];
    __shared__ int s[256];
    __shared__ int cur[RPB];
    int b = blockIdx.x;
    int t = threadIdx.x;
    int base = bbase[b], end = bbase[b + 1];
    int row0 = b << RPB_SHIFT;

    h[t] = 0;
    __syncthreads();
    for (int i = base + t; i < end; i += 256)
        atomicAdd(&h[brow[i] - row0], 1);
    __syncthreads();

    int a = h[t];
    s[t] = a;
    __syncthreads();
    for (int off = 1; off < 256; off <<= 1) {
        int v = (t >= off) ? s[t - off] : 0;
        __syncthreads();
        s[t] += v;
        __syncthreads();
    }
    int excl = s[t] - a;
    cur[t] = excl;
    int gr = row0 + t;
    if (gr < N) rowptr[gr] = base + excl;
    __syncthreads();

    for (int i = base + t; i < end; i += 256) {
        int r = brow[i] - row0;
        int p = atomicAdd(&cur[r], 1);
        csr[base + p] = bcolval[i];
    }
}

// ---------------- MFMA GEMM1: sup1[M,128](bf16) = x[M,128](fp32) @ W1 -------
__global__ __launch_bounds__(256) void gemm_mfma128(
        const float* __restrict__ xa, const float* __restrict__ xb, int na,
        const ushort* __restrict__ Wt, ushort* __restrict__ out, int M) {
    __shared__ ushort sX[64][136];
    __shared__ ushort sW[128][136];
    int t = threadIdx.x;
    int row0 = blockIdx.x * 64;

    #pragma unroll
    for (int i = 0; i < 8; ++i) {
        int idx = i * 256 + t;
        int n = idx >> 4, c8 = (idx & 15) << 3;
        *(uint4*)(&sW[n][c8]) = *(const uint4*)(Wt + n * 128 + c8);
    }
    #pragma unroll
    for (int i = 0; i < 8; ++i) {
        int idx = i * 256 + t;
        int r = idx >> 5, c4 = (idx & 31) << 2;
        int gr = row0 + r;
        float4 v = make_float4(0.f, 0.f, 0.f, 0.f);
        if (gr < M) {
            const float* src = (gr < na) ? (xa + (size_t)gr * 128)
                                         : (xb + (size_t)(gr - na) * 128);
            v = *(const float4*)(src + c4);
        }
        uint2 p;
        p.x = (uint)f2bf(v.x) | ((uint)f2bf(v.y) << 16);
        p.y = (uint)f2bf(v.z) | ((uint)f2bf(v.w) << 16);
        *(uint2*)(&sX[r][c4]) = p;
    }
    __syncthreads();

    int lane = t & 63, w = t >> 6;
    int r0 = w * 16;
    int lrow = lane & 15, lk = (lane >> 4) << 3;
    f32x4 acc[8];
    #pragma unroll
    for (int n = 0; n < 8; ++n) acc[n] = (f32x4){0.f, 0.f, 0.f, 0.f};

    #pragma unroll
    for (int ks = 0; ks < 4; ++ks) {
        bf16x8 a = *(const bf16x8*)(&sX[r0 + lrow][ks * 32 + lk]);
        #pragma unroll
        for (int n = 0; n < 8; ++n) {
            bf16x8 b = *(const bf16x8*)(&sW[n * 16 + lrow][ks * 32 + lk]);
            acc[n] = __builtin_amdgcn_mfma_f32_16x16x32_bf16(a, b, acc[n], 0, 0, 0);
        }
    }
    __syncthreads();
    #pragma unroll
    for (int n = 0; n < 8; ++n)
        #pragma unroll
        for (int r = 0; r < 4; ++r)
            sX[r0 + ((lane >> 4) << 2) + r][n * 16 + lrow] = f2bf(acc[n][r]);
    __syncthreads();
    #pragma unroll
    for (int i = 0; i < 4; ++i) {
        int idx = i * 256 + t;
        int r = idx >> 4, c8 = (idx & 15) << 3;
        int gr = row0 + r;
        if (gr < M)
            *(uint4*)(out + (size_t)gr * 128 + c8) = *(const uint4*)(&sX[r][c8]);
    }
}

// ---------------- FUSED agg1 + gemm2 ----------------
// Block owns 32 rows. Phase 1: 4 waves x 8 rows, full-wave gathers from sup1
// (2 cols/lane), relu(agg+b1) -> LDS bf16 tile. Phase 2: 32x128 @ 128x64 MFMA
// (Wt2 LDS-staged) -> sup2 bf16, coalesced store via LDS bounce.
__global__ __launch_bounds__(256) void agg1_gemm2(
        const ushort* __restrict__ sup1, const int* __restrict__ rowptr,
        const int2* __restrict__ csr, const float* __restrict__ b1,
        const ushort* __restrict__ Wt2, ushort* __restrict__ sup2, int M) {
    __shared__ ushort sH[32][136];
    __shared__ ushort sW[64][136];
    __shared__ ushort sO[32][72];
    int t = threadIdx.x;
    int lane = t & 63, w = t >> 6;
    int row0 = blockIdx.x * 32;

    // stage Wt2 [64][128]
    #pragma unroll
    for (int i = 0; i < 4; ++i) {
        int idx = i * 256 + t;
        int n = idx >> 4, c8 = (idx & 15) << 3;
        *(uint4*)(&sW[n][c8]) = *(const uint4*)(Wt2 + n * 128 + c8);
    }

    // phase 1: aggregate 8 rows per wave
    float2 bias = *(const float2*)(b1 + (lane << 1));
    for (int rr = 0; rr < 8; ++rr) {
        int lr = w * 8 + rr;
        int wid = row0 + lr;
        uint pack = 0;
        if (wid < M) {
            int jb = rowptr[wid], je = rowptr[wid + 1];
            float a0x = 0.f, a0y = 0.f, a1x = 0.f, a1y = 0.f;
            int j = jb;
            for (; j + 8 <= je; j += 8) {
                int2 c[8];
                #pragma unroll
                for (int u = 0; u < 8; ++u) c[u] = csr[j + u];
                uint sv[8];
                #pragma unroll
                for (int u = 0; u < 8; ++u)
                    sv[u] = *(const uint*)(sup1 + ((size_t)c[u].x << 7) + (lane << 1));
                #pragma unroll
                for (int u = 0; u < 8; ++u) {
                    float v = __int_as_float(c[u].y);
                    if (u & 1) { a1x = fmaf(v, bflo(sv[u]), a1x); a1y = fmaf(v, bfhi(sv[u]), a1y); }
                    else       { a0x = fmaf(v, bflo(sv[u]), a0x); a0y = fmaf(v, bfhi(sv[u]), a0y); }
                }
            }
            for (; j < je; ++j) {
                int2 cc = csr[j];
                uint sv = *(const uint*)(sup1 + ((size_t)cc.x << 7) + (lane << 1));
                float v = __int_as_float(cc.y);
                a0x = fmaf(v, bflo(sv), a0x); a0y = fmaf(v, bfhi(sv), a0y);
            }
            float hx = fmaxf(a0x + a1x + bias.x, 0.f);
            float hy = fmaxf(a0y + a1y + bias.y, 0.f);
            pack = (uint)f2bf(hx) | ((uint)f2bf(hy) << 16);
        }
        *(uint*)(&sH[lr][lane << 1]) = pack;
    }
    __syncthreads();

    // phase 2: MFMA 32x128 @ 128x64. wave w: rows (w>>1)*16, cols (w&1)*32
    {
        int lrow = lane & 15, lk = (lane >> 4) << 3;
        int rb = (w >> 1) << 4, cb = (w & 1) << 5;
        f32x4 acc0 = (f32x4){0.f, 0.f, 0.f, 0.f};
        f32x4 acc1 = (f32x4){0.f, 0.f, 0.f, 0.f};
        #pragma unroll
        for (int ks = 0; ks < 4; ++ks) {
            bf16x8 a  = *(const bf16x8*)(&sH[rb + lrow][ks * 32 + lk]);
            bf16x8 b0 = *(const bf16x8*)(&sW[cb + lrow][ks * 32 + lk]);
            bf16x8 b1f= *(const bf16x8*)(&sW[cb + 16 + lrow][ks * 32 + lk]);
            acc0 = __builtin_amdgcn_mfma_f32_16x16x32_bf16(a, b0, acc0, 0, 0, 0);
            acc1 = __builtin_amdgcn_mfma_f32_16x16x32_bf16(a, b1f, acc1, 0, 0, 0);
        }
        int orow = rb + ((lane >> 4) << 2);
        #pragma unroll
        for (int r = 0; r < 4; ++r) {
            sO[orow + r][cb + lrow]      = f2bf(acc0[r]);
            sO[orow + r][cb + 16 + lrow] = f2bf(acc1[r]);
        }
    }
    __syncthreads();

    // store sup2: 32 rows x 64 cols bf16 = 256 uint4s, one per thread
    {
        int r = t >> 3, c8 = (t & 7) << 3;
        int gr = row0 + r;
        if (gr < M)
            *(uint4*)(sup2 + (size_t)gr * 64 + c8) = *(const uint4*)(&sO[r][c8]);
    }
}

// ---------------- agg2: D=64, half-wave per edge, fp32 out ----------------
__global__ __launch_bounds__(256) void agg_kernel64(
        const ushort* __restrict__ sup, const int* __restrict__ rowptr,
        const int2* __restrict__ csr, const float* __restrict__ bias,
        float* __restrict__ out, int M) {
    int wid = (blockIdx.x * 256 + threadIdx.x) >> 6;
    int lane = threadIdx.x & 63;
    if (wid >= M) return;
    int hl = lane & 31, half = lane >> 5;
    int jb = rowptr[wid], je = rowptr[wid + 1];
    float aA0 = 0.f, aA1 = 0.f, aB0 = 0.f, aB1 = 0.f;
    int j = jb;
    for (; j + 16 <= je; j += 16) {
        int2 c[8];
        #pragma unroll
        for (int u = 0; u < 8; ++u) c[u] = csr[j + 2 * u + half];
        uint g[8];
        #pragma unroll
        for (int u = 0; u < 8; ++u)
            g[u] = *(const uint*)(sup + ((size_t)c[u].x << 6) + (hl << 1));
        #pragma unroll
        for (int u = 0; u < 8; ++u) {
            float v = __int_as_float(c[u].y);
            if (u & 1) { aB0 = fmaf(v, bflo(g[u]), aB0); aB1 = fmaf(v, bfhi(g[u]), aB1); }
            else       { aA0 = fmaf(v, bflo(g[u]), aA0); aA1 = fmaf(v, bfhi(g[u]), aA1); }
        }
    }
    for (; j + 2 <= je; j += 2) {
        int2 c = csr[j + half];
        uint g = *(const uint*)(sup + ((size_t)c.x << 6) + (hl << 1));
        float v = __int_as_float(c.y);
        aA0 = fmaf(v, bflo(g), aA0); aA1 = fmaf(v, bfhi(g), aA1);
    }
    if (j < je && half == 0) {
        int2 c = csr[j];
        uint g = *(const uint*)(sup + ((size_t)c.x << 6) + (hl << 1));
        float v = __int_as_float(c.y);
        aA0 = fmaf(v, bflo(g), aA0); aA1 = fmaf(v, bfhi(g), aA1);
    }
    float s0 = aA0 + aB0, s1 = aA1 + aB1;
    s0 += __shfl_xor(s0, 32); s1 += __shfl_xor(s1, 32);
    if (half == 0) {
        float2 b = *(const float2*)(bias + (hl << 1));
        float2 o = make_float2(fmaxf(s0 + b.x, 0.f), fmaxf(s1 + b.y, 0.f));
        *(float2*)(out + (size_t)wid * 64 + (hl << 1)) = o;
    }
}

// ---------------- launch ----------------

extern "C" void kernel_launch(void* const* d_in, const int* in_sizes, int n_in,
                              void* d_out, int out_size, void* d_ws, size_t ws_size,
                              hipStream_t stream) {
    const int*   ei        = (const int*)d_in[0];     // [2, E]
    const float* vals      = (const float*)d_in[1];   // [E]
    const float* emb_node  = (const float*)d_in[2];   // [NN, 128]
    const float* emb_attri = (const float*)d_in[3];   // [NA, 128]
    const float* W1        = (const float*)d_in[4];   // [128, 128]
    const float* b1        = (const float*)d_in[5];   // [128]
    const float* W2        = (const float*)d_in[6];   // [128, 64]
    const float* b2        = (const float*)d_in[7];   // [64]

    const int E  = in_sizes[1];
    const int NN = in_sizes[2] / 128;
    const int NA = in_sizes[3] / 128;
    const int N  = NN + NA;
    const int nbuckets = (N + RPB - 1) >> RPB_SHIFT;   // <= 512

    const int* row = ei;
    const int* col = ei + E;

    // Workspace layout. sup2/brow/bcolval share the second slot (disjoint lifetimes).
    char*  ws   = (char*)d_ws;
    size_t A    = 512;
    size_t Ss   = (((size_t)N * 128 * sizeof(ushort)) + A - 1) / A * A;   // sup1 bf16 (28MB)
    size_t Sh   = (((size_t)N * 128 * sizeof(ushort)) + A - 1) / A * A;   // sup2/bin slot (28MB)
    size_t csrB = (((size_t)E * sizeof(int2))         + A - 1) / A * A;
    size_t rpB  = (((size_t)(N + 1) * sizeof(int))    + A - 1) / A * A;
    size_t browB = (((size_t)E * sizeof(int)) + A - 1) / A * A;

    ushort* sup1   = (ushort*)ws;
    ushort* sup2   = (ushort*)(ws + Ss);
    int*    brow   = (int*)(ws + Ss);                    // aliases sup2 (dead by then)
    int2*   bcolval= (int2*)(ws + Ss + browB);           // aliases sup2
    int2*   csr    = (int2*)(ws + Ss + Sh);
    int*    rowptr = (int*)(ws + Ss + Sh + csrB);
    int*    bcnt   = (int*)(ws + Ss + Sh + csrB + rpB);            // 512 ints
    int*    bbase  = bcnt + MAXB;                                  // 513 ints
    int*    bcur   = bcnt + MAXB + MAXB + 8;                       // 512 ints
    ushort* Wt1    = (ushort*)(ws + Ss + Sh + csrB + rpB + 16384); // 32 KB
    ushort* Wt2    = Wt1 + 128 * 128;                              // 16 KB

    // --- prep + CSR build ---
    prep_kernel<<<96, 256, 0, stream>>>(W1, W2, Wt1, Wt2, bcnt);
    bucket_hist<<<512, 256, 0, stream>>>(row, bcnt, E, nbuckets);
    bucket_scan<<<1, 256, 0, stream>>>(bcnt, bbase, bcur, rowptr, nbuckets, N, E);
    bin_kernel<<<(E + CH - 1) / CH, 256, 0, stream>>>(row, col, vals, bcur, brow, bcolval, E);
    final_scatter<<<nbuckets, 256, 0, stream>>>(bbase, brow, bcolval, rowptr, csr, N);

    // --- Layer 1 GEMM ---
    gemm_mfma128<<<(N + 63) / 64, 256, 0, stream>>>(emb_node, emb_attri, NN, Wt1, sup1, N);
    // --- Fused agg1 + gemm2 ---
    agg1_gemm2<<<(N + 31) / 32, 256, 0, stream>>>(sup1, rowptr, csr, b1, Wt2, sup2, N);
    // --- Layer 2 aggregation ---
    agg_kernel64<<<(N + 3) / 4, 256, 0, stream>>>(sup2, rowptr, csr, b2, (float*)d_out, N);
}

// Round 6
// 309.007 us; speedup vs baseline: 1.0608x; 1.0608x over previous
//
#include <hip/hip_runtime.h>

// ---------------------------------------------------------------------------
// GCN 2-layer pipeline:
//   h1 = relu(spmm(A, x@W1) + b1); out = relu(spmm(A, h1@W2) + b2)
// CSR build: bucket sort (row>>8) -> per-bucket LDS scatter (L2-resident).
// GEMMs: MFMA bf16 (K=128 LDS-resident), separate dispatches.
// agg128: one full wave per row, 2 cols/lane, 8-edge unroll, bf16 out.
// agg64:  half-wave per edge (2 cols/lane), 16 edges in flight, fp32 out.
// R5 lesson: do NOT fuse the gather with MFMA (occupancy + barrier loss).
// ---------------------------------------------------------------------------

typedef unsigned int uint;
typedef unsigned short ushort;
typedef __attribute__((ext_vector_type(8))) short bf16x8;
typedef __attribute__((ext_vector_type(4))) float f32x4;

#define RPB_SHIFT 8
#define RPB 256          // rows per bucket
#define MAXB 512         // max buckets (N <= 131072)
#define CH 2048          // edges per bin-block

__device__ __forceinline__ ushort f2bf(float f) {   // RNE float->bf16
    uint u = __float_as_uint(f);
    u += 0x7fffu + ((u >> 16) & 1u);
    return (ushort)(u >> 16);
}
__device__ __forceinline__ float bflo(uint p) { return __uint_as_float(p << 16); }
__device__ __forceinline__ float bfhi(uint p) { return __uint_as_float(p & 0xffff0000u); }

// ---------------- prep: Wt transpose->bf16 + zero bcnt ----------------
__global__ __launch_bounds__(256) void prep_kernel(const float* __restrict__ W1,
                                                   const float* __restrict__ W2,
                                                   ushort* __restrict__ Wt1,
                                                   ushort* __restrict__ Wt2,
                                                   int* __restrict__ bcnt) {
    int g = blockIdx.x * 256 + threadIdx.x;
    if (g < 16384) { int k = g >> 7, n = g & 127; Wt1[n * 128 + k] = f2bf(W1[g]); }
    else if (g < 24576) { int i = g - 16384; int k = i >> 6, n = i & 63; Wt2[n * 128 + k] = f2bf(W2[i]); }
    if (g < MAXB) bcnt[g] = 0;
}

// ---------------- CSR build ----------------

__global__ __launch_bounds__(256) void bucket_hist(const int* __restrict__ row,
                                                   int* __restrict__ bcnt,
                                                   int E, int nbuckets) {
    __shared__ int h[MAXB];
    int t = threadIdx.x;
    h[t] = 0; h[t + 256] = 0;
    __syncthreads();
    int stride = gridDim.x * blockDim.x;
    for (int e = blockIdx.x * blockDim.x + t; e < E; e += stride)
        atomicAdd(&h[row[e] >> RPB_SHIFT], 1);
    __syncthreads();
    if (h[t] > 0)       atomicAdd(&bcnt[t], h[t]);
    if (h[t + 256] > 0) atomicAdd(&bcnt[t + 256], h[t + 256]);
}

__global__ __launch_bounds__(256) void bucket_scan(const int* __restrict__ bcnt,
                                                   int* __restrict__ bbase,
                                                   int* __restrict__ bcur,
                                                   int* __restrict__ rowptr,
                                                   int nbuckets, int N, int E) {
    __shared__ int s[256];
    int t = threadIdx.x;
    int c0 = bcnt[2 * t], c1 = bcnt[2 * t + 1];
    s[t] = c0 + c1;
    __syncthreads();
    for (int off = 1; off < 256; off <<= 1) {
        int v = (t >= off) ? s[t - off] : 0;
        __syncthreads();
        s[t] += v;
        __syncthreads();
    }
    int excl = s[t] - c0 - c1;
    if (2 * t < nbuckets)     { bbase[2 * t] = excl;          bcur[2 * t] = excl; }
    if (2 * t + 1 < nbuckets) { bbase[2 * t + 1] = excl + c0; bcur[2 * t + 1] = excl + c0; }
    if (t == 0) { bbase[nbuckets] = E; rowptr[N] = E; }
}

__global__ __launch_bounds__(256) void bin_kernel(
        const int* __restrict__ row, const int* __restrict__ col,
        const float* __restrict__ val, int* __restrict__ bcur,
        int* __restrict__ brow, int2* __restrict__ bcolval, int E) {
    __shared__ int ssrow[CH];
    __shared__ int2 scolval[CH];
    __shared__ int hist[MAXB], lbase[MAXB], cur[MAXB], gbase[MAXB];
    __shared__ int s[256];
    int t = threadIdx.x;
    int c0 = blockIdx.x * CH;

    hist[t] = 0; hist[t + 256] = 0;
    __syncthreads();

    int rr[8]; int2 rc[8];
    #pragma unroll
    for (int k = 0; k < 8; ++k) {
        int e = c0 + (k << 8) + t;
        if (e < E) {
            rr[k] = row[e];
            rc[k] = make_int2(col[e], __float_as_int(val[e]));
            atomicAdd(&hist[rr[k] >> RPB_SHIFT], 1);
        } else rr[k] = -1;
    }
    __syncthreads();

    int h0 = hist[2 * t], h1 = hist[2 * t + 1];
    s[t] = h0 + h1;
    __syncthreads();
    for (int off = 1; off < 256; off <<= 1) {
        int v = (t >= off) ? s[t - off] : 0;
        __syncthreads();
        s[t] += v;
        __syncthreads();
    }
    int excl = s[t] - h0 - h1;
    lbase[2 * t] = excl;          cur[2 * t] = excl;
    lbase[2 * t + 1] = excl + h0; cur[2 * t + 1] = excl + h0;
    __syncthreads();
    int total = s[255];

    #pragma unroll
    for (int k = 0; k < 8; ++k) {
        if (rr[k] >= 0) {
            int b = rr[k] >> RPB_SHIFT;
            int p = atomicAdd(&cur[b], 1);
            ssrow[p]   = rr[k];
            scolval[p] = rc[k];
        }
    }
    if (h0 > 0) gbase[2 * t]     = atomicAdd(&bcur[2 * t], h0);
    if (h1 > 0) gbase[2 * t + 1] = atomicAdd(&bcur[2 * t + 1], h1);
    __syncthreads();

    for (int i = t; i < total; i += 256) {
        int r = ssrow[i];
        int b = r >> RPB_SHIFT;
        int g = gbase[b] + (i - lbase[b]);
        brow[g]    = r;
        bcolval[g] = scolval[i];
    }
}

__global__ __launch_bounds__(256) void final_scatter(
        const int* __restrict__ bbase, const int* __restrict__ brow,
        const int2* __restrict__ bcolval, int* __restrict__ rowptr,
        int2* __restrict__ csr, int N) {
    __shared__ int h[RPB];
    __shared__ int s[256];
    __shared__ int cur[RPB];
    int b = blockIdx.x;
    int t = threadIdx.x;
    int base = bbase[b], end = bbase[b + 1];
    int row0 = b << RPB_SHIFT;

    h[t] = 0;
    __syncthreads();
    for (int i = base + t; i < end; i += 256)
        atomicAdd(&h[brow[i] - row0], 1);
    __syncthreads();

    int a = h[t];
    s[t] = a;
    __syncthreads();
    for (int off = 1; off < 256; off <<= 1) {
        int v = (t >= off) ? s[t - off] : 0;
        __syncthreads();
        s[t] += v;
        __syncthreads();
    }
    int excl = s[t] - a;
    cur[t] = excl;
    int gr = row0 + t;
    if (gr < N) rowptr[gr] = base + excl;
    __syncthreads();

    for (int i = base + t; i < end; i += 256) {
        int r = brow[i] - row0;
        int p = atomicAdd(&cur[r], 1);
        csr[base + p] = bcolval[i];
    }
}

// ---------------- MFMA GEMM: out[M,DOUT](bf16) = x[M,128] @ W[128,DOUT] ------
template<int DOUT, bool AB16>
__global__ __launch_bounds__(256) void gemm_mfma(
        const void* __restrict__ xa_, const void* __restrict__ xb_, int na,
        const ushort* __restrict__ Wt, ushort* __restrict__ out, int M) {
    __shared__ ushort sX[64][136];
    __shared__ ushort sW[DOUT][136];
    int t = threadIdx.x;
    int row0 = blockIdx.x * 64;

    #pragma unroll
    for (int i = 0; i < DOUT / 16; ++i) {
        int idx = i * 256 + t;
        int n = idx >> 4, c8 = (idx & 15) << 3;
        *(uint4*)(&sW[n][c8]) = *(const uint4*)(Wt + n * 128 + c8);
    }
    if (AB16) {
        const ushort* xa = (const ushort*)xa_;
        #pragma unroll
        for (int i = 0; i < 4; ++i) {
            int idx = i * 256 + t;
            int r = idx >> 4, c8 = (idx & 15) << 3;
            int gr = row0 + r;
            uint4 v = make_uint4(0, 0, 0, 0);
            if (gr < M) v = *(const uint4*)(xa + (size_t)gr * 128 + c8);
            *(uint4*)(&sX[r][c8]) = v;
        }
    } else {
        const float* xa = (const float*)xa_;
        const float* xb = (const float*)xb_;
        #pragma unroll
        for (int i = 0; i < 8; ++i) {
            int idx = i * 256 + t;
            int r = idx >> 5, c4 = (idx & 31) << 2;
            int gr = row0 + r;
            float4 v = make_float4(0.f, 0.f, 0.f, 0.f);
            if (gr < M) {
                const float* src = (gr < na) ? (xa + (size_t)gr * 128)
                                             : (xb + (size_t)(gr - na) * 128);
                v = *(const float4*)(src + c4);
            }
            uint2 p;
            p.x = (uint)f2bf(v.x) | ((uint)f2bf(v.y) << 16);
            p.y = (uint)f2bf(v.z) | ((uint)f2bf(v.w) << 16);
            *(uint2*)(&sX[r][c4]) = p;
        }
    }
    __syncthreads();

    int lane = t & 63, w = t >> 6;
    int r0 = w * 16;
    int lrow = lane & 15, lk = (lane >> 4) << 3;
    constexpr int NT = DOUT / 16;
    f32x4 acc[NT];
    #pragma unroll
    for (int n = 0; n < NT; ++n) acc[n] = (f32x4){0.f, 0.f, 0.f, 0.f};

    #pragma unroll
    for (int ks = 0; ks < 4; ++ks) {
        bf16x8 a = *(const bf16x8*)(&sX[r0 + lrow][ks * 32 + lk]);
        #pragma unroll
        for (int n = 0; n < NT; ++n) {
            bf16x8 b = *(const bf16x8*)(&sW[n * 16 + lrow][ks * 32 + lk]);
            acc[n] = __builtin_amdgcn_mfma_f32_16x16x32_bf16(a, b, acc[n], 0, 0, 0);
        }
    }
    __syncthreads();
    #pragma unroll
    for (int n = 0; n < NT; ++n)
        #pragma unroll
        for (int r = 0; r < 4; ++r)
            sX[r0 + ((lane >> 4) << 2) + r][n * 16 + lrow] = f2bf(acc[n][r]);
    __syncthreads();
    constexpr int CW = DOUT / 8;
    #pragma unroll
    for (int i = 0; i < DOUT / 32; ++i) {
        int idx = i * 256 + t;
        int r = idx / CW, c8 = (idx % CW) * 8;
        int gr = row0 + r;
        if (gr < M)
            *(uint4*)(out + (size_t)gr * DOUT + c8) = *(const uint4*)(&sX[r][c8]);
    }
}

// ---------------- agg128: full wave per row, 8-edge unroll, bf16 out ---------
__global__ __launch_bounds__(256) void agg_kernel128(
        const ushort* __restrict__ sup, const int* __restrict__ rowptr,
        const int2* __restrict__ csr, const float* __restrict__ bias,
        ushort* __restrict__ out, int M) {
    int wid = (blockIdx.x * 256 + threadIdx.x) >> 6;
    int lane = threadIdx.x & 63;
    if (wid >= M) return;
    int jb = rowptr[wid], je = rowptr[wid + 1];
    float a0x = 0.f, a0y = 0.f, a1x = 0.f, a1y = 0.f;
    int j = jb;
    for (; j + 8 <= je; j += 8) {
        int2 c[8];
        #pragma unroll
        for (int u = 0; u < 8; ++u) c[u] = csr[j + u];
        uint sv[8];
        #pragma unroll
        for (int u = 0; u < 8; ++u)
            sv[u] = *(const uint*)(sup + ((size_t)c[u].x << 7) + (lane << 1));
        #pragma unroll
        for (int u = 0; u < 8; ++u) {
            float v = __int_as_float(c[u].y);
            if (u & 1) { a1x = fmaf(v, bflo(sv[u]), a1x); a1y = fmaf(v, bfhi(sv[u]), a1y); }
            else       { a0x = fmaf(v, bflo(sv[u]), a0x); a0y = fmaf(v, bfhi(sv[u]), a0y); }
        }
    }
    for (; j < je; ++j) {
        int2 cc = csr[j];
        uint sv = *(const uint*)(sup + ((size_t)cc.x << 7) + (lane << 1));
        float v = __int_as_float(cc.y);
        a0x = fmaf(v, bflo(sv), a0x); a0y = fmaf(v, bfhi(sv), a0y);
    }
    float2 b = *(const float2*)(bias + (lane << 1));
    float hx = fmaxf(a0x + a1x + b.x, 0.f);
    float hy = fmaxf(a0y + a1y + b.y, 0.f);
    uint p = (uint)f2bf(hx) | ((uint)f2bf(hy) << 16);
    *(uint*)(out + (size_t)wid * 128 + (lane << 1)) = p;
}

// ---------------- agg64: half-wave per edge, fp32 out ----------------
__global__ __launch_bounds__(256) void agg_kernel64(
        const ushort* __restrict__ sup, const int* __restrict__ rowptr,
        const int2* __restrict__ csr, const float* __restrict__ bias,
        float* __restrict__ out, int M) {
    int wid = (blockIdx.x * 256 + threadIdx.x) >> 6;
    int lane = threadIdx.x & 63;
    if (wid >= M) return;
    int hl = lane & 31, half = lane >> 5;
    int jb = rowptr[wid], je = rowptr[wid + 1];
    float aA0 = 0.f, aA1 = 0.f, aB0 = 0.f, aB1 = 0.f;
    int j = jb;
    for (; j + 16 <= je; j += 16) {
        int2 c[8];
        #pragma unroll
        for (int u = 0; u < 8; ++u) c[u] = csr[j + 2 * u + half];
        uint g[8];
        #pragma unroll
        for (int u = 0; u < 8; ++u)
            g[u] = *(const uint*)(sup + ((size_t)c[u].x << 6) + (hl << 1));
        #pragma unroll
        for (int u = 0; u < 8; ++u) {
            float v = __int_as_float(c[u].y);
            if (u & 1) { aB0 = fmaf(v, bflo(g[u]), aB0); aB1 = fmaf(v, bfhi(g[u]), aB1); }
            else       { aA0 = fmaf(v, bflo(g[u]), aA0); aA1 = fmaf(v, bfhi(g[u]), aA1); }
        }
    }
    for (; j + 2 <= je; j += 2) {
        int2 c = csr[j + half];
        uint g = *(const uint*)(sup + ((size_t)c.x << 6) + (hl << 1));
        float v = __int_as_float(c.y);
        aA0 = fmaf(v, bflo(g), aA0); aA1 = fmaf(v, bfhi(g), aA1);
    }
    if (j < je && half == 0) {
        int2 c = csr[j];
        uint g = *(const uint*)(sup + ((size_t)c.x << 6) + (hl << 1));
        float v = __int_as_float(c.y);
        aA0 = fmaf(v, bflo(g), aA0); aA1 = fmaf(v, bfhi(g), aA1);
    }
    float s0 = aA0 + aB0, s1 = aA1 + aB1;
    s0 += __shfl_xor(s0, 32); s1 += __shfl_xor(s1, 32);
    if (half == 0) {
        float2 b = *(const float2*)(bias + (hl << 1));
        float2 o = make_float2(fmaxf(s0 + b.x, 0.f), fmaxf(s1 + b.y, 0.f));
        *(float2*)(out + (size_t)wid * 64 + (hl << 1)) = o;
    }
}

// ---------------- launch ----------------

extern "C" void kernel_launch(void* const* d_in, const int* in_sizes, int n_in,
                              void* d_out, int out_size, void* d_ws, size_t ws_size,
                              hipStream_t stream) {
    const int*   ei        = (const int*)d_in[0];     // [2, E]
    const float* vals      = (const float*)d_in[1];   // [E]
    const float* emb_node  = (const float*)d_in[2];   // [NN, 128]
    const float* emb_attri = (const float*)d_in[3];   // [NA, 128]
    const float* W1        = (const float*)d_in[4];   // [128, 128]
    const float* b1        = (const float*)d_in[5];   // [128]
    const float* W2        = (const float*)d_in[6];   // [128, 64]
    const float* b2        = (const float*)d_in[7];   // [64]

    const int E  = in_sizes[1];
    const int NN = in_sizes[2] / 128;
    const int NA = in_sizes[3] / 128;
    const int N  = NN + NA;
    const int nbuckets = (N + RPB - 1) >> RPB_SHIFT;   // <= 512

    const int* row = ei;
    const int* col = ei + E;

    // Workspace layout (~73 MiB). sup reused by both layers; brow/bcolval
    // alias the h1 slot (dead until agg128 writes it).
    char*  ws   = (char*)d_ws;
    size_t A    = 512;
    size_t Ss   = (((size_t)N * 128 * sizeof(ushort)) + A - 1) / A * A;   // sup bf16
    size_t Sh   = (((size_t)N * 128 * sizeof(ushort)) + A - 1) / A * A;   // h1 bf16 / bin slot
    size_t csrB = (((size_t)E * sizeof(int2))         + A - 1) / A * A;
    size_t rpB  = (((size_t)(N + 1) * sizeof(int))    + A - 1) / A * A;
    size_t browB = (((size_t)E * sizeof(int)) + A - 1) / A * A;

    ushort* sup    = (ushort*)ws;
    ushort* h1     = (ushort*)(ws + Ss);
    int*    brow   = (int*)(ws + Ss);                    // aliases h1
    int2*   bcolval= (int2*)(ws + Ss + browB);           // aliases h1 (24MB <= 28MB)
    int2*   csr    = (int2*)(ws + Ss + Sh);
    int*    rowptr = (int*)(ws + Ss + Sh + csrB);
    int*    bcnt   = (int*)(ws + Ss + Sh + csrB + rpB);            // 512 ints
    int*    bbase  = bcnt + MAXB;                                  // 513 ints
    int*    bcur   = bcnt + MAXB + MAXB + 8;                       // 512 ints
    ushort* Wt1    = (ushort*)(ws + Ss + Sh + csrB + rpB + 16384); // 32 KB
    ushort* Wt2    = Wt1 + 128 * 128;                              // 16 KB

    // --- prep + CSR build ---
    prep_kernel<<<96, 256, 0, stream>>>(W1, W2, Wt1, Wt2, bcnt);
    bucket_hist<<<512, 256, 0, stream>>>(row, bcnt, E, nbuckets);
    bucket_scan<<<1, 256, 0, stream>>>(bcnt, bbase, bcur, rowptr, nbuckets, N, E);
    bin_kernel<<<(E + CH - 1) / CH, 256, 0, stream>>>(row, col, vals, bcur, brow, bcolval, E);
    final_scatter<<<nbuckets, 256, 0, stream>>>(bbase, brow, bcolval, rowptr, csr, N);

    int gblocks = (N + 63) / 64;
    int ablocks = (N + 3) / 4;

    // --- Layer 1 ---
    gemm_mfma<128, false><<<gblocks, 256, 0, stream>>>(emb_node, emb_attri, NN, Wt1, sup, N);
    agg_kernel128<<<ablocks, 256, 0, stream>>>(sup, rowptr, csr, b1, h1, N);

    // --- Layer 2 ---
    gemm_mfma<64, true><<<gblocks, 256, 0, stream>>>(h1, h1, N, Wt2, sup, N);
    agg_kernel64<<<ablocks, 256, 0, stream>>>(sup, rowptr, csr, b2, (float*)d_out, N);
}

// Round 7
// 280.897 us; speedup vs baseline: 1.1669x; 1.1001x over previous
//
#include <hip/hip_runtime.h>

// ---------------------------------------------------------------------------
// GCN 2-layer pipeline:
//   h1 = relu(spmm(A, x@W1) + b1); out = relu(spmm(A, h1@W2) + b2)
// CSR build: bucket sort (row>>8) -> per-bucket LDS scatter (L2-resident).
// hist merged into gemm128's grid (independent work, one dispatch).
// agg128: full wave per row, 2 cols/lane, 16-edge unroll (16 gathers in
//         flight), scalarized row bounds, bf16 out.
// agg64:  quarter-wave (16 lanes) per edge, 4 cols/lane, 32 edges in flight.
// R5 lesson: no gather+MFMA fusion. R4 lesson: don't split agg128's wave.
// ---------------------------------------------------------------------------

typedef unsigned int uint;
typedef unsigned short ushort;
typedef __attribute__((ext_vector_type(8))) short bf16x8;
typedef __attribute__((ext_vector_type(4))) float f32x4;

#define RPB_SHIFT 8
#define RPB 256          // rows per bucket
#define MAXB 512         // max buckets (N <= 131072)
#define CH 2048          // edges per bin-block
#define HB 512           // hist blocks inside hist_gemm

__device__ __forceinline__ ushort f2bf(float f) {   // RNE float->bf16
    uint u = __float_as_uint(f);
    u += 0x7fffu + ((u >> 16) & 1u);
    return (ushort)(u >> 16);
}
__device__ __forceinline__ float bflo(uint p) { return __uint_as_float(p << 16); }
__device__ __forceinline__ float bfhi(uint p) { return __uint_as_float(p & 0xffff0000u); }

// ---------------- prep: Wt transpose->bf16 + zero bcnt ----------------
__global__ __launch_bounds__(256) void prep_kernel(const float* __restrict__ W1,
                                                   const float* __restrict__ W2,
                                                   ushort* __restrict__ Wt1,
                                                   ushort* __restrict__ Wt2,
                                                   int* __restrict__ bcnt) {
    int g = blockIdx.x * 256 + threadIdx.x;
    if (g < 16384) { int k = g >> 7, n = g & 127; Wt1[n * 128 + k] = f2bf(W1[g]); }
    else if (g < 24576) { int i = g - 16384; int k = i >> 6, n = i & 63; Wt2[n * 128 + k] = f2bf(W2[i]); }
    if (g < MAXB) bcnt[g] = 0;
}

// ---------------- hist + gemm128 in one grid ----------------
// blocks [0, HB): per-bucket edge hist (LDS-aggregated -> atomicAdd bcnt).
// blocks [HB, HB+gblocks): sup1[M,128](bf16) = x[M,128](fp32) @ W1 (MFMA).
__global__ __launch_bounds__(256) void hist_gemm(
        const int* __restrict__ row, int* __restrict__ bcnt, int E,
        const float* __restrict__ xa, const float* __restrict__ xb, int na,
        const ushort* __restrict__ Wt, ushort* __restrict__ out, int M) {
    __shared__ char smem[52224];   // max(hist 2KB, gemm sX 17408 + sW 34816)
    int t = threadIdx.x;

    if ((int)blockIdx.x < HB) {
        int* h = (int*)smem;
        h[t] = 0; h[t + 256] = 0;
        __syncthreads();
        const int stride = HB * 256;
        for (int e = blockIdx.x * 256 + t; e < E; e += stride)
            atomicAdd(&h[row[e] >> RPB_SHIFT], 1);
        __syncthreads();
        if (h[t] > 0)       atomicAdd(&bcnt[t], h[t]);
        if (h[t + 256] > 0) atomicAdd(&bcnt[t + 256], h[t + 256]);
        return;
    }

    // ---- gemm128 path ----
    ushort (*sX)[136] = (ushort(*)[136])smem;
    ushort (*sW)[136] = (ushort(*)[136])(smem + 64 * 136 * 2);
    int row0 = ((int)blockIdx.x - HB) * 64;

    #pragma unroll
    for (int i = 0; i < 8; ++i) {
        int idx = i * 256 + t;
        int n = idx >> 4, c8 = (idx & 15) << 3;
        *(uint4*)(&sW[n][c8]) = *(const uint4*)(Wt + n * 128 + c8);
    }
    #pragma unroll
    for (int i = 0; i < 8; ++i) {
        int idx = i * 256 + t;
        int r = idx >> 5, c4 = (idx & 31) << 2;
        int gr = row0 + r;
        float4 v = make_float4(0.f, 0.f, 0.f, 0.f);
        if (gr < M) {
            const float* src = (gr < na) ? (xa + (size_t)gr * 128)
                                         : (xb + (size_t)(gr - na) * 128);
            v = *(const float4*)(src + c4);
        }
        uint2 p;
        p.x = (uint)f2bf(v.x) | ((uint)f2bf(v.y) << 16);
        p.y = (uint)f2bf(v.z) | ((uint)f2bf(v.w) << 16);
        *(uint2*)(&sX[r][c4]) = p;
    }
    __syncthreads();

    int lane = t & 63, w = t >> 6;
    int r0 = w * 16;
    int lrow = lane & 15, lk = (lane >> 4) << 3;
    f32x4 acc[8];
    #pragma unroll
    for (int n = 0; n < 8; ++n) acc[n] = (f32x4){0.f, 0.f, 0.f, 0.f};

    #pragma unroll
    for (int ks = 0; ks < 4; ++ks) {
        bf16x8 a = *(const bf16x8*)(&sX[r0 + lrow][ks * 32 + lk]);
        #pragma unroll
        for (int n = 0; n < 8; ++n) {
            bf16x8 b = *(const bf16x8*)(&sW[n * 16 + lrow][ks * 32 + lk]);
            acc[n] = __builtin_amdgcn_mfma_f32_16x16x32_bf16(a, b, acc[n], 0, 0, 0);
        }
    }
    __syncthreads();
    #pragma unroll
    for (int n = 0; n < 8; ++n)
        #pragma unroll
        for (int r = 0; r < 4; ++r)
            sX[r0 + ((lane >> 4) << 2) + r][n * 16 + lrow] = f2bf(acc[n][r]);
    __syncthreads();
    #pragma unroll
    for (int i = 0; i < 4; ++i) {
        int idx = i * 256 + t;
        int r = idx >> 4, c8 = (idx & 15) << 3;
        int gr = row0 + r;
        if (gr < M)
            *(uint4*)(out + (size_t)gr * 128 + c8) = *(const uint4*)(&sX[r][c8]);
    }
}

// ---------------- CSR build (scan, bin, final) ----------------

__global__ __launch_bounds__(256) void bucket_scan(const int* __restrict__ bcnt,
                                                   int* __restrict__ bbase,
                                                   int* __restrict__ bcur,
                                                   int* __restrict__ rowptr,
                                                   int nbuckets, int N, int E) {
    __shared__ int s[256];
    int t = threadIdx.x;
    int c0 = bcnt[2 * t], c1 = bcnt[2 * t + 1];
    s[t] = c0 + c1;
    __syncthreads();
    for (int off = 1; off < 256; off <<= 1) {
        int v = (t >= off) ? s[t - off] : 0;
        __syncthreads();
        s[t] += v;
        __syncthreads();
    }
    int excl = s[t] - c0 - c1;
    if (2 * t < nbuckets)     { bbase[2 * t] = excl;          bcur[2 * t] = excl; }
    if (2 * t + 1 < nbuckets) { bbase[2 * t + 1] = excl + c0; bcur[2 * t + 1] = excl + c0; }
    if (t == 0) { bbase[nbuckets] = E; rowptr[N] = E; }
}

__global__ __launch_bounds__(256) void bin_kernel(
        const int* __restrict__ row, const int* __restrict__ col,
        const float* __restrict__ val, int* __restrict__ bcur,
        int* __restrict__ brow, int2* __restrict__ bcolval, int E) {
    __shared__ int ssrow[CH];
    __shared__ int2 scolval[CH];
    __shared__ int hist[MAXB], lbase[MAXB], cur[MAXB], gbase[MAXB];
    __shared__ int s[256];
    int t = threadIdx.x;
    int c0 = blockIdx.x * CH;

    hist[t] = 0; hist[t + 256] = 0;
    __syncthreads();

    int rr[8]; int2 rc[8];
    #pragma unroll
    for (int k = 0; k < 8; ++k) {
        int e = c0 + (k << 8) + t;
        if (e < E) {
            rr[k] = row[e];
            rc[k] = make_int2(col[e], __float_as_int(val[e]));
            atomicAdd(&hist[rr[k] >> RPB_SHIFT], 1);
        } else rr[k] = -1;
    }
    __syncthreads();

    int h0 = hist[2 * t], h1 = hist[2 * t + 1];
    s[t] = h0 + h1;
    __syncthreads();
    for (int off = 1; off < 256; off <<= 1) {
        int v = (t >= off) ? s[t - off] : 0;
        __syncthreads();
        s[t] += v;
        __syncthreads();
    }
    int excl = s[t] - h0 - h1;
    lbase[2 * t] = excl;          cur[2 * t] = excl;
    lbase[2 * t + 1] = excl + h0; cur[2 * t + 1] = excl + h0;
    __syncthreads();
    int total = s[255];

    #pragma unroll
    for (int k = 0; k < 8; ++k) {
        if (rr[k] >= 0) {
            int b = rr[k] >> RPB_SHIFT;
            int p = atomicAdd(&cur[b], 1);
            ssrow[p]   = rr[k];
            scolval[p] = rc[k];
        }
    }
    if (h0 > 0) gbase[2 * t]     = atomicAdd(&bcur[2 * t], h0);
    if (h1 > 0) gbase[2 * t + 1] = atomicAdd(&bcur[2 * t + 1], h1);
    __syncthreads();

    for (int i = t; i < total; i += 256) {
        int r = ssrow[i];
        int b = r >> RPB_SHIFT;
        int g = gbase[b] + (i - lbase[b]);
        brow[g]    = r;
        bcolval[g] = scolval[i];
    }
}

__global__ __launch_bounds__(256) void final_scatter(
        const int* __restrict__ bbase, const int* __restrict__ brow,
        const int2* __restrict__ bcolval, int* __restrict__ rowptr,
        int2* __restrict__ csr, int N) {
    __shared__ int h[RPB];
    __shared__ int s[256];
    __shared__ int cur[RPB];
    int b = blockIdx.x;
    int t = threadIdx.x;
    int base = bbase[b], end = bbase[b + 1];
    int row0 = b << RPB_SHIFT;

    h[t] = 0;
    __syncthreads();
    for (int i = base + t; i < end; i += 256)
        atomicAdd(&h[brow[i] - row0], 1);
    __syncthreads();

    int a = h[t];
    s[t] = a;
    __syncthreads();
    for (int off = 1; off < 256; off <<= 1) {
        int v = (t >= off) ? s[t - off] : 0;
        __syncthreads();
        s[t] += v;
        __syncthreads();
    }
    int excl = s[t] - a;
    cur[t] = excl;
    int gr = row0 + t;
    if (gr < N) rowptr[gr] = base + excl;
    __syncthreads();

    for (int i = base + t; i < end; i += 256) {
        int r = brow[i] - row0;
        int p = atomicAdd(&cur[r], 1);
        csr[base + p] = bcolval[i];
    }
}

// ---------------- MFMA GEMM2: sup2[M,64](bf16) = h1[M,128](bf16) @ W2 -------
__global__ __launch_bounds__(256) void gemm_mfma64(
        const ushort* __restrict__ xa, const ushort* __restrict__ Wt,
        ushort* __restrict__ out, int M) {
    __shared__ ushort sX[64][136];
    __shared__ ushort sW[64][136];
    int t = threadIdx.x;
    int row0 = blockIdx.x * 64;

    #pragma unroll
    for (int i = 0; i < 4; ++i) {
        int idx = i * 256 + t;
        int n = idx >> 4, c8 = (idx & 15) << 3;
        *(uint4*)(&sW[n][c8]) = *(const uint4*)(Wt + n * 128 + c8);
    }
    #pragma unroll
    for (int i = 0; i < 4; ++i) {
        int idx = i * 256 + t;
        int r = idx >> 4, c8 = (idx & 15) << 3;
        int gr = row0 + r;
        uint4 v = make_uint4(0, 0, 0, 0);
        if (gr < M) v = *(const uint4*)(xa + (size_t)gr * 128 + c8);
        *(uint4*)(&sX[r][c8]) = v;
    }
    __syncthreads();

    int lane = t & 63, w = t >> 6;
    int r0 = w * 16;
    int lrow = lane & 15, lk = (lane >> 4) << 3;
    f32x4 acc[4];
    #pragma unroll
    for (int n = 0; n < 4; ++n) acc[n] = (f32x4){0.f, 0.f, 0.f, 0.f};

    #pragma unroll
    for (int ks = 0; ks < 4; ++ks) {
        bf16x8 a = *(const bf16x8*)(&sX[r0 + lrow][ks * 32 + lk]);
        #pragma unroll
        for (int n = 0; n < 4; ++n) {
            bf16x8 b = *(const bf16x8*)(&sW[n * 16 + lrow][ks * 32 + lk]);
            acc[n] = __builtin_amdgcn_mfma_f32_16x16x32_bf16(a, b, acc[n], 0, 0, 0);
        }
    }
    __syncthreads();
    #pragma unroll
    for (int n = 0; n < 4; ++n)
        #pragma unroll
        for (int r = 0; r < 4; ++r)
            sX[r0 + ((lane >> 4) << 2) + r][n * 16 + lrow] = f2bf(acc[n][r]);
    __syncthreads();
    #pragma unroll
    for (int i = 0; i < 2; ++i) {
        int idx = i * 256 + t;
        int r = idx >> 3, c8 = (idx & 7) << 3;
        int gr = row0 + r;
        if (gr < M)
            *(uint4*)(out + (size_t)gr * 64 + c8) = *(const uint4*)(&sX[r][c8]);
    }
}

// ---------------- agg128: full wave/row, 16-edge unroll, bf16 out ------------
__global__ __launch_bounds__(256) void agg_kernel128(
        const ushort* __restrict__ sup, const int* __restrict__ rowptr,
        const int2* __restrict__ csr, const float* __restrict__ bias,
        ushort* __restrict__ out, int M) {
    int wid = (blockIdx.x * 256 + threadIdx.x) >> 6;
    int lane = threadIdx.x & 63;
    if (wid >= M) return;
    int jb = __builtin_amdgcn_readfirstlane(rowptr[wid]);
    int je = __builtin_amdgcn_readfirstlane(rowptr[wid + 1]);
    const char* supb = (const char*)sup;
    uint loff = (uint)lane << 2;
    float a0x = 0.f, a0y = 0.f, a1x = 0.f, a1y = 0.f;
    float a2x = 0.f, a2y = 0.f, a3x = 0.f, a3y = 0.f;
    int j = jb;
    for (; j + 16 <= je; j += 16) {
        int2 c[16];
        #pragma unroll
        for (int u = 0; u < 16; ++u) c[u] = csr[j + u];
        uint sv[16];
        #pragma unroll
        for (int u = 0; u < 16; ++u)
            sv[u] = *(const uint*)(supb + ((((uint)c[u].x) << 8) | loff));
        #pragma unroll
        for (int u = 0; u < 16; ++u) {
            float v = __int_as_float(c[u].y);
            float lo = bflo(sv[u]), hi = bfhi(sv[u]);
            switch (u & 3) {
                case 0: a0x = fmaf(v, lo, a0x); a0y = fmaf(v, hi, a0y); break;
                case 1: a1x = fmaf(v, lo, a1x); a1y = fmaf(v, hi, a1y); break;
                case 2: a2x = fmaf(v, lo, a2x); a2y = fmaf(v, hi, a2y); break;
                default: a3x = fmaf(v, lo, a3x); a3y = fmaf(v, hi, a3y); break;
            }
        }
    }
    for (; j + 4 <= je; j += 4) {
        int2 c[4];
        #pragma unroll
        for (int u = 0; u < 4; ++u) c[u] = csr[j + u];
        uint sv[4];
        #pragma unroll
        for (int u = 0; u < 4; ++u)
            sv[u] = *(const uint*)(supb + ((((uint)c[u].x) << 8) | loff));
        #pragma unroll
        for (int u = 0; u < 4; ++u) {
            float v = __int_as_float(c[u].y);
            if (u & 1) { a1x = fmaf(v, bflo(sv[u]), a1x); a1y = fmaf(v, bfhi(sv[u]), a1y); }
            else       { a0x = fmaf(v, bflo(sv[u]), a0x); a0y = fmaf(v, bfhi(sv[u]), a0y); }
        }
    }
    for (; j < je; ++j) {
        int2 cc = csr[j];
        uint sv = *(const uint*)(supb + ((((uint)cc.x) << 8) | loff));
        float v = __int_as_float(cc.y);
        a0x = fmaf(v, bflo(sv), a0x); a0y = fmaf(v, bfhi(sv), a0y);
    }
    float2 b = *(const float2*)(bias + (lane << 1));
    float hx = fmaxf(a0x + a1x + a2x + a3x + b.x, 0.f);
    float hy = fmaxf(a0y + a1y + a2y + a3y + b.y, 0.f);
    uint p = (uint)f2bf(hx) | ((uint)f2bf(hy) << 16);
    *(uint*)(out + ((size_t)wid << 7) + (lane << 1)) = p;
}

// ---------------- agg64: quarter-wave per edge, 32 in flight, fp32 out -------
__global__ __launch_bounds__(256) void agg_kernel64(
        const ushort* __restrict__ sup, const int* __restrict__ rowptr,
        const int2* __restrict__ csr, const float* __restrict__ bias,
        float* __restrict__ out, int M) {
    int wid = (blockIdx.x * 256 + threadIdx.x) >> 6;
    int lane = threadIdx.x & 63;
    if (wid >= M) return;
    int ql = lane & 15, q = lane >> 4;
    int jb = __builtin_amdgcn_readfirstlane(rowptr[wid]);
    int je = __builtin_amdgcn_readfirstlane(rowptr[wid + 1]);
    const char* supb = (const char*)sup;
    uint loff = (uint)ql << 3;
    float s0 = 0.f, s1 = 0.f, s2 = 0.f, s3 = 0.f;
    float t0 = 0.f, t1 = 0.f, t2 = 0.f, t3 = 0.f;
    int j = jb;
    for (; j + 32 <= je; j += 32) {
        int2 c[8];
        #pragma unroll
        for (int u = 0; u < 8; ++u) c[u] = csr[j + 4 * u + q];
        uint2 g[8];
        #pragma unroll
        for (int u = 0; u < 8; ++u)
            g[u] = *(const uint2*)(supb + ((((uint)c[u].x) << 7) | loff));
        #pragma unroll
        for (int u = 0; u < 8; ++u) {
            float v = __int_as_float(c[u].y);
            if (u & 1) {
                t0 = fmaf(v, bflo(g[u].x), t0); t1 = fmaf(v, bfhi(g[u].x), t1);
                t2 = fmaf(v, bflo(g[u].y), t2); t3 = fmaf(v, bfhi(g[u].y), t3);
            } else {
                s0 = fmaf(v, bflo(g[u].x), s0); s1 = fmaf(v, bfhi(g[u].x), s1);
                s2 = fmaf(v, bflo(g[u].y), s2); s3 = fmaf(v, bfhi(g[u].y), s3);
            }
        }
    }
    for (; j + 4 <= je; j += 4) {
        int2 c = csr[j + q];
        uint2 g = *(const uint2*)(supb + ((((uint)c.x) << 7) | loff));
        float v = __int_as_float(c.y);
        s0 = fmaf(v, bflo(g.x), s0); s1 = fmaf(v, bfhi(g.x), s1);
        s2 = fmaf(v, bflo(g.y), s2); s3 = fmaf(v, bfhi(g.y), s3);
    }
    int rem = je - j;
    if (q < rem) {
        int2 c = csr[j + q];
        uint2 g = *(const uint2*)(supb + ((((uint)c.x) << 7) | loff));
        float v = __int_as_float(c.y);
        s0 = fmaf(v, bflo(g.x), s0); s1 = fmaf(v, bfhi(g.x), s1);
        s2 = fmaf(v, bflo(g.y), s2); s3 = fmaf(v, bfhi(g.y), s3);
    }
    s0 += t0; s1 += t1; s2 += t2; s3 += t3;
    s0 += __shfl_xor(s0, 16); s0 += __shfl_xor(s0, 32);
    s1 += __shfl_xor(s1, 16); s1 += __shfl_xor(s1, 32);
    s2 += __shfl_xor(s2, 16); s2 += __shfl_xor(s2, 32);
    s3 += __shfl_xor(s3, 16); s3 += __shfl_xor(s3, 32);
    if (q == 0) {
        float4 b = *(const float4*)(bias + (ql << 2));
        float4 o = make_float4(fmaxf(s0 + b.x, 0.f), fmaxf(s1 + b.y, 0.f),
                               fmaxf(s2 + b.z, 0.f), fmaxf(s3 + b.w, 0.f));
        *(float4*)(out + ((size_t)wid << 6) + (ql << 2)) = o;
    }
}

// ---------------- launch ----------------

extern "C" void kernel_launch(void* const* d_in, const int* in_sizes, int n_in,
                              void* d_out, int out_size, void* d_ws, size_t ws_size,
                              hipStream_t stream) {
    const int*   ei        = (const int*)d_in[0];     // [2, E]
    const float* vals      = (const float*)d_in[1];   // [E]
    const float* emb_node  = (const float*)d_in[2];   // [NN, 128]
    const float* emb_attri = (const float*)d_in[3];   // [NA, 128]
    const float* W1        = (const float*)d_in[4];   // [128, 128]
    const float* b1        = (const float*)d_in[5];   // [128]
    const float* W2        = (const float*)d_in[6];   // [128, 64]
    const float* b2        = (const float*)d_in[7];   // [64]

    const int E  = in_sizes[1];
    const int NN = in_sizes[2] / 128;
    const int NA = in_sizes[3] / 128;
    const int N  = NN + NA;
    const int nbuckets = (N + RPB - 1) >> RPB_SHIFT;   // <= 512

    const int* row = ei;
    const int* col = ei + E;

    // Workspace layout (~73 MiB). sup reused by both layers; brow/bcolval
    // alias the h1 slot (dead until agg128 writes it).
    char*  ws   = (char*)d_ws;
    size_t A    = 512;
    size_t Ss   = (((size_t)N * 128 * sizeof(ushort)) + A - 1) / A * A;   // sup bf16
    size_t Sh   = (((size_t)N * 128 * sizeof(ushort)) + A - 1) / A * A;   // h1 bf16 / bin slot
    size_t csrB = (((size_t)E * sizeof(int2))         + A - 1) / A * A;
    size_t rpB  = (((size_t)(N + 1) * sizeof(int))    + A - 1) / A * A;
    size_t browB = (((size_t)E * sizeof(int)) + A - 1) / A * A;

    ushort* sup    = (ushort*)ws;
    ushort* h1     = (ushort*)(ws + Ss);
    int*    brow   = (int*)(ws + Ss);                    // aliases h1
    int2*   bcolval= (int2*)(ws + Ss + browB);           // aliases h1 (24MB <= 28MB)
    int2*   csr    = (int2*)(ws + Ss + Sh);
    int*    rowptr = (int*)(ws + Ss + Sh + csrB);
    int*    bcnt   = (int*)(ws + Ss + Sh + csrB + rpB);            // 512 ints
    int*    bbase  = bcnt + MAXB;                                  // 513 ints
    int*    bcur   = bcnt + MAXB + MAXB + 8;                       // 512 ints
    ushort* Wt1    = (ushort*)(ws + Ss + Sh + csrB + rpB + 16384); // 32 KB
    ushort* Wt2    = Wt1 + 128 * 128;                              // 16 KB

    int gblocks = (N + 63) / 64;
    int ablocks = (N + 3) / 4;

    // 1. prep (Wt1, Wt2, zero bcnt)
    prep_kernel<<<96, 256, 0, stream>>>(W1, W2, Wt1, Wt2, bcnt);
    // 2. hist + gemm128 (independent work, one grid)
    hist_gemm<<<HB + gblocks, 256, 0, stream>>>(row, bcnt, E,
                                                emb_node, emb_attri, NN, Wt1, sup, N);
    // 3-5. CSR build
    bucket_scan<<<1, 256, 0, stream>>>(bcnt, bbase, bcur, rowptr, nbuckets, N, E);
    bin_kernel<<<(E + CH - 1) / CH, 256, 0, stream>>>(row, col, vals, bcur, brow, bcolval, E);
    final_scatter<<<nbuckets, 256, 0, stream>>>(bbase, brow, bcolval, rowptr, csr, N);
    // 6. layer-1 aggregation
    agg_kernel128<<<ablocks, 256, 0, stream>>>(sup, rowptr, csr, b1, h1, N);
    // 7. layer-2 GEMM
    gemm_mfma64<<<gblocks, 256, 0, stream>>>(h1, Wt2, sup, N);
    // 8. layer-2 aggregation
    agg_kernel64<<<ablocks, 256, 0, stream>>>(sup, rowptr, csr, b2, (float*)d_out, N);
}

// Round 8
// 263.157 us; speedup vs baseline: 1.2456x; 1.0674x over previous
//
#include <hip/hip_runtime.h>

// ---------------------------------------------------------------------------
// GCN 2-layer pipeline:
//   h1 = relu(spmm(A, x@W1) + b1); out = relu(spmm(A, h1@W2) + b2)
// CSR build: bucket sort (row>>8) -> per-bucket LDS scatter (L2-resident).
// R8: bin merged with gemm128 (stall-heavy + compute-heavy overlap);
//     hist -> per-block partials (merged with Wt prep, no zeroing dep);
//     all block scans -> shfl wave-scans (2 barriers instead of 16).
// agg128: full wave/row, 16-edge unroll. agg64: quarter-wave, 32 in flight.
// R5 lesson: no gather+MFMA fusion. R4 lesson: don't split agg128's wave.
// ---------------------------------------------------------------------------

typedef unsigned int uint;
typedef unsigned short ushort;
typedef __attribute__((ext_vector_type(8))) short bf16x8;
typedef __attribute__((ext_vector_type(4))) float f32x4;

#define RPB_SHIFT 8
#define RPB 256          // rows per bucket
#define MAXB 512         // max buckets (N <= 131072)
#define CH 2048          // edges per bin-block
#define HB 512           // hist blocks in histprep

__device__ __forceinline__ ushort f2bf(float f) {   // RNE float->bf16
    uint u = __float_as_uint(f);
    u += 0x7fffu + ((u >> 16) & 1u);
    return (ushort)(u >> 16);
}
__device__ __forceinline__ float bflo(uint p) { return __uint_as_float(p << 16); }
__device__ __forceinline__ float bfhi(uint p) { return __uint_as_float(p & 0xffff0000u); }

// wave-inclusive scan of v (64 lanes)
__device__ __forceinline__ int wscan(int v, int lane) {
    #pragma unroll
    for (int off = 1; off < 64; off <<= 1) {
        int u = __shfl_up(v, off);
        if (lane >= off) v += u;
    }
    return v;
}

// ---------------- histprep: per-block bucket hist partials + Wt prep --------
__global__ __launch_bounds__(256) void histprep(const int* __restrict__ row,
                                                int* __restrict__ partial, int E,
                                                const float* __restrict__ W1,
                                                const float* __restrict__ W2,
                                                ushort* __restrict__ Wt1,
                                                ushort* __restrict__ Wt2) {
    int t = threadIdx.x;
    if ((int)blockIdx.x < HB) {
        __shared__ int h[MAXB];
        h[t] = 0; h[t + 256] = 0;
        __syncthreads();
        const int stride = HB * 256;
        for (int e = blockIdx.x * 256 + t; e < E; e += stride)
            atomicAdd(&h[row[e] >> RPB_SHIFT], 1);
        __syncthreads();
        partial[blockIdx.x * MAXB + t]       = h[t];
        partial[blockIdx.x * MAXB + 256 + t] = h[t + 256];
        return;
    }
    int g = ((int)blockIdx.x - HB) * 256 + t;
    if (g < 16384) { int k = g >> 7, n = g & 127; Wt1[n * 128 + k] = f2bf(W1[g]); }
    else if (g < 24576) { int i = g - 16384; int k = i >> 6, n = i & 63; Wt2[n * 128 + k] = f2bf(W2[i]); }
}

// ---------------- bucket_scan: sum partials + exclusive scan ----------------
__global__ __launch_bounds__(256) void bucket_scan(const int* __restrict__ partial,
                                                   int* __restrict__ bbase,
                                                   int* __restrict__ bcur,
                                                   int* __restrict__ rowptr,
                                                   int nbuckets, int N, int E) {
    __shared__ int wsum[4];
    int t = threadIdx.x;
    int lane = t & 63, w = t >> 6;
    int c0 = 0, c1 = 0;
    #pragma unroll 8
    for (int blk = 0; blk < HB; ++blk) {
        int2 p = *(const int2*)(partial + blk * MAXB + 2 * t);
        c0 += p.x; c1 += p.y;
    }
    int s = c0 + c1;
    int v = wscan(s, lane);
    if (lane == 63) wsum[w] = v;
    __syncthreads();
    int woff = 0;
    #pragma unroll
    for (int k = 0; k < 4; ++k) if (k < w) woff += wsum[k];
    int excl = v + woff - s;
    if (2 * t < nbuckets)     { bbase[2 * t] = excl;          bcur[2 * t] = excl; }
    if (2 * t + 1 < nbuckets) { bbase[2 * t + 1] = excl + c0; bcur[2 * t + 1] = excl + c0; }
    if (t == 0) { bbase[nbuckets] = E; rowptr[N] = E; }
}

// ---------------- bin + gemm128 in one grid ----------------
// blocks [0, BB): counting-sort CH edges by bucket, burst-write to brow/bcolval.
// blocks [BB, ...): sup1[M,128](bf16) = x[M,128](fp32) @ W1 (MFMA).
__global__ __launch_bounds__(256) void bin_gemm(
        const int* __restrict__ row, const int* __restrict__ col,
        const float* __restrict__ val, int* __restrict__ bcur,
        int* __restrict__ brow, int2* __restrict__ bcolval, int E, int BB,
        const float* __restrict__ xa, const float* __restrict__ xb, int na,
        const ushort* __restrict__ Wt, ushort* __restrict__ out, int M) {
    __shared__ char smem[52224];   // gemm: sX 17408 + sW 34816; bin overlays 32.8KB
    int t = threadIdx.x;

    if ((int)blockIdx.x < BB) {
        // ---- bin path ----
        int*  ssrow   = (int*)smem;                 //  8KB
        int2* scolval = (int2*)(smem + 8192);       // 16KB
        int*  hist    = (int*)(smem + 24576);       //  2KB
        int*  lbase   = (int*)(smem + 26624);       //  2KB
        int*  cur     = (int*)(smem + 28672);       //  2KB
        int*  gbase   = (int*)(smem + 30720);       //  2KB
        int*  wsum    = (int*)(smem + 32768);       //  16B
        int lane = t & 63, w = t >> 6;

        hist[t] = 0; hist[t + 256] = 0;
        __syncthreads();
        int c0 = blockIdx.x * CH;
        int rr[8]; int2 rc[8];
        #pragma unroll
        for (int k = 0; k < 8; ++k) {
            int e = c0 + (k << 8) + t;
            if (e < E) {
                rr[k] = row[e];
                rc[k] = make_int2(col[e], __float_as_int(val[e]));
                atomicAdd(&hist[rr[k] >> RPB_SHIFT], 1);
            } else rr[k] = -1;
        }
        __syncthreads();

        int h0 = hist[2 * t], h1 = hist[2 * t + 1];
        int s = h0 + h1;
        int v = wscan(s, lane);
        if (lane == 63) wsum[w] = v;
        __syncthreads();
        int woff = 0, tot = 0;
        #pragma unroll
        for (int k = 0; k < 4; ++k) { int x = wsum[k]; tot += x; if (k < w) woff += x; }
        int excl = v + woff - s;
        lbase[2 * t] = excl;          cur[2 * t] = excl;
        lbase[2 * t + 1] = excl + h0; cur[2 * t + 1] = excl + h0;
        __syncthreads();

        #pragma unroll
        for (int k = 0; k < 8; ++k) {
            if (rr[k] >= 0) {
                int b = rr[k] >> RPB_SHIFT;
                int p = atomicAdd(&cur[b], 1);
                ssrow[p]   = rr[k];
                scolval[p] = rc[k];
            }
        }
        if (h0 > 0) gbase[2 * t]     = atomicAdd(&bcur[2 * t], h0);
        if (h1 > 0) gbase[2 * t + 1] = atomicAdd(&bcur[2 * t + 1], h1);
        __syncthreads();

        for (int i = t; i < tot; i += 256) {
            int r = ssrow[i];
            int b = r >> RPB_SHIFT;
            int g = gbase[b] + (i - lbase[b]);
            brow[g]    = r;
            bcolval[g] = scolval[i];
        }
        return;
    }

    // ---- gemm128 path ----
    ushort (*sX)[136] = (ushort(*)[136])smem;
    ushort (*sW)[136] = (ushort(*)[136])(smem + 64 * 136 * 2);
    int row0 = ((int)blockIdx.x - BB) * 64;

    #pragma unroll
    for (int i = 0; i < 8; ++i) {
        int idx = i * 256 + t;
        int n = idx >> 4, c8 = (idx & 15) << 3;
        *(uint4*)(&sW[n][c8]) = *(const uint4*)(Wt + n * 128 + c8);
    }
    #pragma unroll
    for (int i = 0; i < 8; ++i) {
        int idx = i * 256 + t;
        int r = idx >> 5, c4 = (idx & 31) << 2;
        int gr = row0 + r;
        float4 v = make_float4(0.f, 0.f, 0.f, 0.f);
        if (gr < M) {
            const float* src = (gr < na) ? (xa + (size_t)gr * 128)
                                         : (xb + (size_t)(gr - na) * 128);
            v = *(const float4*)(src + c4);
        }
        uint2 p;
        p.x = (uint)f2bf(v.x) | ((uint)f2bf(v.y) << 16);
        p.y = (uint)f2bf(v.z) | ((uint)f2bf(v.w) << 16);
        *(uint2*)(&sX[r][c4]) = p;
    }
    __syncthreads();

    int lane = t & 63, w = t >> 6;
    int r0 = w * 16;
    int lrow = lane & 15, lk = (lane >> 4) << 3;
    f32x4 acc[8];
    #pragma unroll
    for (int n = 0; n < 8; ++n) acc[n] = (f32x4){0.f, 0.f, 0.f, 0.f};

    #pragma unroll
    for (int ks = 0; ks < 4; ++ks) {
        bf16x8 a = *(const bf16x8*)(&sX[r0 + lrow][ks * 32 + lk]);
        #pragma unroll
        for (int n = 0; n < 8; ++n) {
            bf16x8 b = *(const bf16x8*)(&sW[n * 16 + lrow][ks * 32 + lk]);
            acc[n] = __builtin_amdgcn_mfma_f32_16x16x32_bf16(a, b, acc[n], 0, 0, 0);
        }
    }
    __syncthreads();
    #pragma unroll
    for (int n = 0; n < 8; ++n)
        #pragma unroll
        for (int r = 0; r < 4; ++r)
            sX[r0 + ((lane >> 4) << 2) + r][n * 16 + lrow] = f2bf(acc[n][r]);
    __syncthreads();
    #pragma unroll
    for (int i = 0; i < 4; ++i) {
        int idx = i * 256 + t;
        int r = idx >> 4, c8 = (idx & 15) << 3;
        int gr = row0 + r;
        if (gr < M)
            *(uint4*)(out + (size_t)gr * 128 + c8) = *(const uint4*)(&sX[r][c8]);
    }
}

// ---------------- final_scatter (wave-scan) ----------------
__global__ __launch_bounds__(256) void final_scatter(
        const int* __restrict__ bbase, const int* __restrict__ brow,
        const int2* __restrict__ bcolval, int* __restrict__ rowptr,
        int2* __restrict__ csr, int N) {
    __shared__ int h[RPB];
    __shared__ int cur[RPB];
    __shared__ int wsum[4];
    int b = blockIdx.x;
    int t = threadIdx.x;
    int lane = t & 63, w = t >> 6;
    int base = bbase[b], end = bbase[b + 1];
    int row0 = b << RPB_SHIFT;

    h[t] = 0;
    __syncthreads();
    for (int i = base + t; i < end; i += 256)
        atomicAdd(&h[brow[i] - row0], 1);
    __syncthreads();

    int a = h[t];
    int v = wscan(a, lane);
    if (lane == 63) wsum[w] = v;
    __syncthreads();
    int woff = 0;
    #pragma unroll
    for (int k = 0; k < 4; ++k) if (k < w) woff += wsum[k];
    int excl = v + woff - a;
    cur[t] = excl;
    int gr = row0 + t;
    if (gr < N) rowptr[gr] = base + excl;
    __syncthreads();

    for (int i = base + t; i < end; i += 256) {
        int r = brow[i] - row0;
        int p = atomicAdd(&cur[r], 1);
        csr[base + p] = bcolval[i];
    }
}

// ---------------- MFMA GEMM2: sup2[M,64](bf16) = h1[M,128](bf16) @ W2 -------
__global__ __launch_bounds__(256) void gemm_mfma64(
        const ushort* __restrict__ xa, const ushort* __restrict__ Wt,
        ushort* __restrict__ out, int M) {
    __shared__ ushort sX[64][136];
    __shared__ ushort sW[64][136];
    int t = threadIdx.x;
    int row0 = blockIdx.x * 64;

    #pragma unroll
    for (int i = 0; i < 4; ++i) {
        int idx = i * 256 + t;
        int n = idx >> 4, c8 = (idx & 15) << 3;
        *(uint4*)(&sW[n][c8]) = *(const uint4*)(Wt + n * 128 + c8);
    }
    #pragma unroll
    for (int i = 0; i < 4; ++i) {
        int idx = i * 256 + t;
        int r = idx >> 4, c8 = (idx & 15) << 3;
        int gr = row0 + r;
        uint4 v = make_uint4(0, 0, 0, 0);
        if (gr < M) v = *(const uint4*)(xa + (size_t)gr * 128 + c8);
        *(uint4*)(&sX[r][c8]) = v;
    }
    __syncthreads();

    int lane = t & 63, w = t >> 6;
    int r0 = w * 16;
    int lrow = lane & 15, lk = (lane >> 4) << 3;
    f32x4 acc[4];
    #pragma unroll
    for (int n = 0; n < 4; ++n) acc[n] = (f32x4){0.f, 0.f, 0.f, 0.f};

    #pragma unroll
    for (int ks = 0; ks < 4; ++ks) {
        bf16x8 a = *(const bf16x8*)(&sX[r0 + lrow][ks * 32 + lk]);
        #pragma unroll
        for (int n = 0; n < 4; ++n) {
            bf16x8 b = *(const bf16x8*)(&sW[n * 16 + lrow][ks * 32 + lk]);
            acc[n] = __builtin_amdgcn_mfma_f32_16x16x32_bf16(a, b, acc[n], 0, 0, 0);
        }
    }
    __syncthreads();
    #pragma unroll
    for (int n = 0; n < 4; ++n)
        #pragma unroll
        for (int r = 0; r < 4; ++r)
            sX[r0 + ((lane >> 4) << 2) + r][n * 16 + lrow] = f2bf(acc[n][r]);
    __syncthreads();
    #pragma unroll
    for (int i = 0; i < 2; ++i) {
        int idx = i * 256 + t;
        int r = idx >> 3, c8 = (idx & 7) << 3;
        int gr = row0 + r;
        if (gr < M)
            *(uint4*)(out + (size_t)gr * 64 + c8) = *(const uint4*)(&sX[r][c8]);
    }
}

// ---------------- agg128: full wave/row, 16-edge unroll, bf16 out ------------
__global__ __launch_bounds__(256) void agg_kernel128(
        const ushort* __restrict__ sup, const int* __restrict__ rowptr,
        const int2* __restrict__ csr, const float* __restrict__ bias,
        ushort* __restrict__ out, int M) {
    int wid = (blockIdx.x * 256 + threadIdx.x) >> 6;
    int lane = threadIdx.x & 63;
    if (wid >= M) return;
    int jb = __builtin_amdgcn_readfirstlane(rowptr[wid]);
    int je = __builtin_amdgcn_readfirstlane(rowptr[wid + 1]);
    const char* supb = (const char*)sup;
    uint loff = (uint)lane << 2;
    float a0x = 0.f, a0y = 0.f, a1x = 0.f, a1y = 0.f;
    float a2x = 0.f, a2y = 0.f, a3x = 0.f, a3y = 0.f;
    int j = jb;
    for (; j + 16 <= je; j += 16) {
        int2 c[16];
        #pragma unroll
        for (int u = 0; u < 16; ++u) c[u] = csr[j + u];
        uint sv[16];
        #pragma unroll
        for (int u = 0; u < 16; ++u)
            sv[u] = *(const uint*)(supb + ((((uint)c[u].x) << 8) | loff));
        #pragma unroll
        for (int u = 0; u < 16; ++u) {
            float v = __int_as_float(c[u].y);
            float lo = bflo(sv[u]), hi = bfhi(sv[u]);
            switch (u & 3) {
                case 0: a0x = fmaf(v, lo, a0x); a0y = fmaf(v, hi, a0y); break;
                case 1: a1x = fmaf(v, lo, a1x); a1y = fmaf(v, hi, a1y); break;
                case 2: a2x = fmaf(v, lo, a2x); a2y = fmaf(v, hi, a2y); break;
                default: a3x = fmaf(v, lo, a3x); a3y = fmaf(v, hi, a3y); break;
            }
        }
    }
    for (; j + 4 <= je; j += 4) {
        int2 c[4];
        #pragma unroll
        for (int u = 0; u < 4; ++u) c[u] = csr[j + u];
        uint sv[4];
        #pragma unroll
        for (int u = 0; u < 4; ++u)
            sv[u] = *(const uint*)(supb + ((((uint)c[u].x) << 8) | loff));
        #pragma unroll
        for (int u = 0; u < 4; ++u) {
            float v = __int_as_float(c[u].y);
            if (u & 1) { a1x = fmaf(v, bflo(sv[u]), a1x); a1y = fmaf(v, bfhi(sv[u]), a1y); }
            else       { a0x = fmaf(v, bflo(sv[u]), a0x); a0y = fmaf(v, bfhi(sv[u]), a0y); }
        }
    }
    for (; j < je; ++j) {
        int2 cc = csr[j];
        uint sv = *(const uint*)(supb + ((((uint)cc.x) << 8) | loff));
        float v = __int_as_float(cc.y);
        a0x = fmaf(v, bflo(sv), a0x); a0y = fmaf(v, bfhi(sv), a0y);
    }
    float2 b = *(const float2*)(bias + (lane << 1));
    float hx = fmaxf(a0x + a1x + a2x + a3x + b.x, 0.f);
    float hy = fmaxf(a0y + a1y + a2y + a3y + b.y, 0.f);
    uint p = (uint)f2bf(hx) | ((uint)f2bf(hy) << 16);
    *(uint*)(out + ((size_t)wid << 7) + (lane << 1)) = p;
}

// ---------------- agg64: quarter-wave per edge, 32 in flight, fp32 out -------
__global__ __launch_bounds__(256) void agg_kernel64(
        const ushort* __restrict__ sup, const int* __restrict__ rowptr,
        const int2* __restrict__ csr, const float* __restrict__ bias,
        float* __restrict__ out, int M) {
    int wid = (blockIdx.x * 256 + threadIdx.x) >> 6;
    int lane = threadIdx.x & 63;
    if (wid >= M) return;
    int ql = lane & 15, q = lane >> 4;
    int jb = __builtin_amdgcn_readfirstlane(rowptr[wid]);
    int je = __builtin_amdgcn_readfirstlane(rowptr[wid + 1]);
    const char* supb = (const char*)sup;
    uint loff = (uint)ql << 3;
    float s0 = 0.f, s1 = 0.f, s2 = 0.f, s3 = 0.f;
    float t0 = 0.f, t1 = 0.f, t2 = 0.f, t3 = 0.f;
    int j = jb;
    for (; j + 32 <= je; j += 32) {
        int2 c[8];
        #pragma unroll
        for (int u = 0; u < 8; ++u) c[u] = csr[j + 4 * u + q];
        uint2 g[8];
        #pragma unroll
        for (int u = 0; u < 8; ++u)
            g[u] = *(const uint2*)(supb + ((((uint)c[u].x) << 7) | loff));
        #pragma unroll
        for (int u = 0; u < 8; ++u) {
            float v = __int_as_float(c[u].y);
            if (u & 1) {
                t0 = fmaf(v, bflo(g[u].x), t0); t1 = fmaf(v, bfhi(g[u].x), t1);
                t2 = fmaf(v, bflo(g[u].y), t2); t3 = fmaf(v, bfhi(g[u].y), t3);
            } else {
                s0 = fmaf(v, bflo(g[u].x), s0); s1 = fmaf(v, bfhi(g[u].x), s1);
                s2 = fmaf(v, bflo(g[u].y), s2); s3 = fmaf(v, bfhi(g[u].y), s3);
            }
        }
    }
    for (; j + 4 <= je; j += 4) {
        int2 c = csr[j + q];
        uint2 g = *(const uint2*)(supb + ((((uint)c.x) << 7) | loff));
        float v = __int_as_float(c.y);
        s0 = fmaf(v, bflo(g.x), s0); s1 = fmaf(v, bfhi(g.x), s1);
        s2 = fmaf(v, bflo(g.y), s2); s3 = fmaf(v, bfhi(g.y), s3);
    }
    int rem = je - j;
    if (q < rem) {
        int2 c = csr[j + q];
        uint2 g = *(const uint2*)(supb + ((((uint)c.x) << 7) | loff));
        float v = __int_as_float(c.y);
        s0 = fmaf(v, bflo(g.x), s0); s1 = fmaf(v, bfhi(g.x), s1);
        s2 = fmaf(v, bflo(g.y), s2); s3 = fmaf(v, bfhi(g.y), s3);
    }
    s0 += t0; s1 += t1; s2 += t2; s3 += t3;
    s0 += __shfl_xor(s0, 16); s0 += __shfl_xor(s0, 32);
    s1 += __shfl_xor(s1, 16); s1 += __shfl_xor(s1, 32);
    s2 += __shfl_xor(s2, 16); s2 += __shfl_xor(s2, 32);
    s3 += __shfl_xor(s3, 16); s3 += __shfl_xor(s3, 32);
    if (q == 0) {
        float4 b = *(const float4*)(bias + (ql << 2));
        float4 o = make_float4(fmaxf(s0 + b.x, 0.f), fmaxf(s1 + b.y, 0.f),
                               fmaxf(s2 + b.z, 0.f), fmaxf(s3 + b.w, 0.f));
        *(float4*)(out + ((size_t)wid << 6) + (ql << 2)) = o;
    }
}

// ---------------- launch ----------------

extern "C" void kernel_launch(void* const* d_in, const int* in_sizes, int n_in,
                              void* d_out, int out_size, void* d_ws, size_t ws_size,
                              hipStream_t stream) {
    const int*   ei        = (const int*)d_in[0];     // [2, E]
    const float* vals      = (const float*)d_in[1];   // [E]
    const float* emb_node  = (const float*)d_in[2];   // [NN, 128]
    const float* emb_attri = (const float*)d_in[3];   // [NA, 128]
    const float* W1        = (const float*)d_in[4];   // [128, 128]
    const float* b1        = (const float*)d_in[5];   // [128]
    const float* W2        = (const float*)d_in[6];   // [128, 64]
    const float* b2        = (const float*)d_in[7];   // [64]

    const int E  = in_sizes[1];
    const int NN = in_sizes[2] / 128;
    const int NA = in_sizes[3] / 128;
    const int N  = NN + NA;
    const int nbuckets = (N + RPB - 1) >> RPB_SHIFT;   // <= 512

    const int* row = ei;
    const int* col = ei + E;

    // Workspace layout (~75 MiB). sup reused by both layers; brow/bcolval
    // alias the h1 slot (dead until agg128 writes it).
    char*  ws   = (char*)d_ws;
    size_t A    = 512;
    size_t Ss   = (((size_t)N * 128 * sizeof(ushort)) + A - 1) / A * A;   // sup bf16
    size_t Sh   = (((size_t)N * 128 * sizeof(ushort)) + A - 1) / A * A;   // h1 bf16 / bin slot
    size_t csrB = (((size_t)E * sizeof(int2))         + A - 1) / A * A;
    size_t rpB  = (((size_t)(N + 1) * sizeof(int))    + A - 1) / A * A;
    size_t browB = (((size_t)E * sizeof(int)) + A - 1) / A * A;

    ushort* sup    = (ushort*)ws;
    ushort* h1     = (ushort*)(ws + Ss);
    int*    brow   = (int*)(ws + Ss);                    // aliases h1
    int2*   bcolval= (int2*)(ws + Ss + browB);           // aliases h1 (24MB <= 28MB)
    int2*   csr    = (int2*)(ws + Ss + Sh);
    int*    rowptr = (int*)(ws + Ss + Sh + csrB);
    char*   meta   = ws + Ss + Sh + csrB + rpB;
    int*    bbase  = (int*)meta;                          // 513 ints
    int*    bcur   = (int*)(meta + 2560);                 // 512 ints
    ushort* Wt1    = (ushort*)(meta + 8192);              // 32 KB
    ushort* Wt2    = (ushort*)(meta + 8192 + 32768);      // 16 KB
    int*    partial= (int*)(meta + 57344);                // 512*512 ints = 1 MB

    int gblocks = (N + 63) / 64;
    int ablocks = (N + 3) / 4;
    int BB = (E + CH - 1) / CH;

    // 1. hist partials + Wt prep (one grid, independent blocks)
    histprep<<<HB + 96, 256, 0, stream>>>(row, partial, E, W1, W2, Wt1, Wt2);
    // 2. sum partials + bucket scan
    bucket_scan<<<1, 256, 0, stream>>>(partial, bbase, bcur, rowptr, nbuckets, N, E);
    // 3. bin (stall-heavy) + gemm128 (compute-heavy) overlapped in one grid
    bin_gemm<<<BB + gblocks, 256, 0, stream>>>(row, col, vals, bcur, brow, bcolval,
                                               E, BB, emb_node, emb_attri, NN, Wt1, sup, N);
    // 4. per-bucket row sort -> rowptr + csr
    final_scatter<<<nbuckets, 256, 0, stream>>>(bbase, brow, bcolval, rowptr, csr, N);
    // 5. layer-1 aggregation
    agg_kernel128<<<ablocks, 256, 0, stream>>>(sup, rowptr, csr, b1, h1, N);
    // 6. layer-2 GEMM
    gemm_mfma64<<<gblocks, 256, 0, stream>>>(h1, Wt2, sup, N);
    // 7. layer-2 aggregation
    agg_kernel64<<<ablocks, 256, 0, stream>>>(sup, rowptr, csr, b2, (float*)d_out, N);
}